// Round 7
// baseline (747.921 us; speedup 1.0000x reference)
//
#include <hip/hip_runtime.h>

typedef _Float16 half8 __attribute__((ext_vector_type(8)));
typedef _Float16 half2v __attribute__((ext_vector_type(2)));
typedef float f32x4 __attribute__((ext_vector_type(4)));

#define S_LEN 4096
#define D_DIM 4096
#define HD 128

// ws layout (6 MiB): qw [8192][128] f16 @0; kw @2MiB; vt [2][128][4096] f16 @4MiB

// ---------------- kernel 1: QKV projection GEMM (f16 MFMA) ----------------
// grid (3, 128): bx = projection, by = 64-row m-tile -> 384 blocks (all 256 CUs busy).
// 4 waves; wave-tile 64M x 32N (8 MFMA per 6 ds_read_b128). BK=32.
// 2-deep register prefetch + double-buffered LDS: slab i+2 issued at iter i,
// consumed at iter i+2 -> ~1.5 iters of latency slack; one barrier per iter.
#define ASTR 40   // staging row stride (f16)
#define QSTR 136  // epilogue row stride (f16)
__global__ __launch_bounds__(256) void proj_kernel(const float* __restrict__ x,
                                                   const float* __restrict__ wq,
                                                   const float* __restrict__ wk,
                                                   const float* __restrict__ wv,
                                                   _Float16* __restrict__ qw,
                                                   _Float16* __restrict__ kw,
                                                   _Float16* __restrict__ vt) {
    __shared__ __align__(16) _Float16 smem[17408];  // 34.8 KB: 2x staging / epilogue union
    const int tid = threadIdx.x;
    const int bx = blockIdx.x;
    const int M0 = blockIdx.y * 64;
    const float* w = (bx == 0) ? wq : (bx == 1) ? wk : wv;
    const int lane = tid & 63, wv_ = tid >> 6;
    const int l15 = lane & 15, quad = lane >> 4;

    // staging: A 64x32 f32 (8 floats/thread), B 128x32 f32 (16 floats/thread)
    const int arow = tid >> 2, acol = (tid & 3) * 8;
    const int brow = tid >> 1, bcol = (tid & 1) * 16;
    const float* xa = x + (size_t)(M0 + arow) * D_DIM + acol;
    const float* wb = w + (size_t)brow * D_DIM + bcol;

    f32x4 acc[4][2];
    for (int mi = 0; mi < 4; ++mi)
        for (int ni = 0; ni < 2; ++ni)
            acc[mi][ni] = (f32x4){0.f, 0.f, 0.f, 0.f};

    float4 pa[2][2], pb[2][4];
    pa[0][0] = *(const float4*)(xa);      pa[0][1] = *(const float4*)(xa + 4);
    pb[0][0] = *(const float4*)(wb);      pb[0][1] = *(const float4*)(wb + 4);
    pb[0][2] = *(const float4*)(wb + 8);  pb[0][3] = *(const float4*)(wb + 12);
    pa[1][0] = *(const float4*)(xa + 32); pa[1][1] = *(const float4*)(xa + 36);
    pb[1][0] = *(const float4*)(wb + 32); pb[1][1] = *(const float4*)(wb + 36);
    pb[1][2] = *(const float4*)(wb + 40); pb[1][3] = *(const float4*)(wb + 44);

    for (int i = 0; i < 128; ++i) {
        const int p = i & 1;
        _Float16* Ash = smem + p * 7680;
        _Float16* Bsh = smem + p * 7680 + 2560;
        half8 ha = { (_Float16)pa[p][0].x, (_Float16)pa[p][0].y, (_Float16)pa[p][0].z, (_Float16)pa[p][0].w,
                     (_Float16)pa[p][1].x, (_Float16)pa[p][1].y, (_Float16)pa[p][1].z, (_Float16)pa[p][1].w };
        half8 hb0 = { (_Float16)pb[p][0].x, (_Float16)pb[p][0].y, (_Float16)pb[p][0].z, (_Float16)pb[p][0].w,
                      (_Float16)pb[p][1].x, (_Float16)pb[p][1].y, (_Float16)pb[p][1].z, (_Float16)pb[p][1].w };
        half8 hb1 = { (_Float16)pb[p][2].x, (_Float16)pb[p][2].y, (_Float16)pb[p][2].z, (_Float16)pb[p][2].w,
                      (_Float16)pb[p][3].x, (_Float16)pb[p][3].y, (_Float16)pb[p][3].z, (_Float16)pb[p][3].w };
        *(half8*)&Ash[arow * ASTR + acol] = ha;
        *(half8*)&Bsh[brow * ASTR + bcol] = hb0;
        *(half8*)&Bsh[brow * ASTR + bcol + 8] = hb1;
        if (i + 2 < 128) {  // issue slab i+2 now; consumed at iter i+2
            const int off = (i + 2) * 32;
            pa[p][0] = *(const float4*)(xa + off);      pa[p][1] = *(const float4*)(xa + off + 4);
            pb[p][0] = *(const float4*)(wb + off);      pb[p][1] = *(const float4*)(wb + off + 4);
            pb[p][2] = *(const float4*)(wb + off + 8);  pb[p][3] = *(const float4*)(wb + off + 12);
        }
        __syncthreads();
        half8 af[4], bf[2];
        for (int mi = 0; mi < 4; ++mi)
            af[mi] = *(const half8*)&Ash[(mi * 16 + l15) * ASTR + quad * 8];
        for (int ni = 0; ni < 2; ++ni)
            bf[ni] = *(const half8*)&Bsh[(wv_ * 32 + ni * 16 + l15) * ASTR + quad * 8];
        for (int mi = 0; mi < 4; ++mi)
            for (int ni = 0; ni < 2; ++ni)
                acc[mi][ni] = __builtin_amdgcn_mfma_f32_16x16x32_f16(af[mi], bf[ni],
                                                                     acc[mi][ni], 0, 0, 0);
        // no trailing barrier: next iter writes the other buffer; its barrier
        // separates these reads from the next overwrite of this buffer
    }
    __syncthreads();

    // ---- epilogue via LDS (coalesced 16B stores). C row(M) = mi*16+quad*4+r,
    // col(N/hd) = wv_*32 + ni*16 + l15 ----
    if (bx < 2) {
        for (int mi = 0; mi < 4; ++mi)
            for (int ni = 0; ni < 2; ++ni)
                for (int r = 0; r < 4; ++r)
                    smem[(mi * 16 + quad * 4 + r) * QSTR + wv_ * 32 + ni * 16 + l15] =
                        (_Float16)acc[mi][ni][r];
        __syncthreads();
        _Float16* dst = ((bx == 0) ? qw : kw) + (size_t)M0 * HD;
        const int row = tid >> 2, c0 = (tid & 3) * 32;
        for (int j = 0; j < 4; ++j)
            *(half8*)&dst[row * HD + c0 + j * 8] = *(const half8*)&smem[row * QSTR + c0 + j * 8];
    } else {
        // transpose in LDS: smem[hd][s_local]
        for (int mi = 0; mi < 4; ++mi)
            for (int ni = 0; ni < 2; ++ni)
                for (int r = 0; r < 4; ++r)
                    smem[(wv_ * 32 + ni * 16 + l15) * QSTR + mi * 16 + quad * 4 + r] =
                        (_Float16)acc[mi][ni][r];
        __syncthreads();
        _Float16* dst = vt + (size_t)(M0 >> 12) * HD * S_LEN + (M0 & (S_LEN - 1));
        const int hd = tid >> 1, s0 = (tid & 1) * 32;
        for (int j = 0; j < 4; ++j)
            *(half8*)&dst[(size_t)hd * S_LEN + s0 + j * 8] =
                *(const half8*)&smem[hd * QSTR + s0 + j * 8];
    }
}

// ---------------- kernel 2: RoPE on q,k in place (verified, unchanged) ----------------
__global__ __launch_bounds__(256) void rope_kernel(_Float16* __restrict__ qw,
                                                   _Float16* __restrict__ kw) {
    const int g = blockIdx.x * 256 + threadIdx.x;  // 524288
    const int m = g >> 6, p = g & 63;
    const int s = m & (S_LEN - 1);
    const float theta = exp2f((float)p * -0.4152410118609203f);  // 10000^(-p/32)
    float sn, cn;
    sincosf((float)s * theta, &sn, &cn);
    const size_t off = (size_t)m * HD + 2 * p;
    half2v qv = *(half2v*)&qw[off];
    half2v kv = *(half2v*)&kw[off];
    float q0 = qv[0], q1 = qv[1], k0 = kv[0], k1 = kv[1];
    half2v qo = { (_Float16)(q0 * cn - q1 * sn), (_Float16)(q1 * cn + q0 * sn) };
    half2v ko = { (_Float16)(k0 * cn - k1 * sn), (_Float16)(k1 * cn + k0 * sn) };
    *(half2v*)&qw[off] = qo;
    *(half2v*)&kw[off] = ko;
}

// ---------------- kernel 3: attention — R3-verified core + K-frag prefetch ----------------
__device__ __forceinline__ void load_kf(const _Float16* __restrict__ kb, int kbase,
                                        int l15, int quad, half8* kf) {
    const _Float16* kr = kb + (size_t)(kbase + l15) * HD + quad * 8;
    for (int kk = 0; kk < 4; ++kk) {
        kf[kk]     = *(const half8*)(kr + kk * 32);
        kf[4 + kk] = *(const half8*)(kr + 16 * HD + kk * 32);
    }
}

template<bool MASKED>
__device__ __forceinline__ void attn_tile(int kbase, int qg, int l15, int quad,
                                          const half8* kf,
                                          const _Float16* __restrict__ vtb,
                                          const half8* bq, f32x4* acc,
                                          float& mrun, float& lrun) {
    const float csc = 0.1275174348796053f;  // (1/sqrt(128)) * log2(e)
    f32x4 st0 = (f32x4){0.f, 0.f, 0.f, 0.f};
    f32x4 st1 = (f32x4){0.f, 0.f, 0.f, 0.f};
    for (int kk = 0; kk < 4; ++kk) {
        st0 = __builtin_amdgcn_mfma_f32_16x16x32_f16(kf[kk],     bq[kk], st0, 0, 0, 0);
        st1 = __builtin_amdgcn_mfma_f32_16x16x32_f16(kf[4 + kk], bq[kk], st1, 0, 0, 0);
    }
    half8 va[8];
    const _Float16* vr = vtb + (size_t)l15 * S_LEN + kbase + quad * 8;
    for (int c = 0; c < 8; ++c)
        va[c] = *(const half8*)(vr + (size_t)c * 16 * S_LEN);
    float p0[4], p1[4];
    float mloc = -1e30f;
    for (int r = 0; r < 4; ++r) {
        float v0 = st0[r] * csc;
        float v1 = st1[r] * csc;
        if (MASKED) {
            const int key0 = kbase + quad * 4 + r;
            if (key0 > qg)      v0 = -1e30f;
            if (key0 + 16 > qg) v1 = -1e30f;
        }
        p0[r] = v0; p1[r] = v1;
        mloc = fmaxf(mloc, fmaxf(v0, v1));
    }
    mloc = fmaxf(mloc, __shfl_xor(mloc, 16));
    mloc = fmaxf(mloc, __shfl_xor(mloc, 32));
    const float mnew = fmaxf(mrun, mloc);
    const float alpha = exp2f(mrun - mnew);
    mrun = mnew;
    float ls = 0.f;
    for (int r = 0; r < 4; ++r) {
        p0[r] = exp2f(p0[r] - mnew);
        p1[r] = exp2f(p1[r] - mnew);
        ls += p0[r] + p1[r];
    }
    ls += __shfl_xor(ls, 16);
    ls += __shfl_xor(ls, 32);
    lrun = lrun * alpha + ls;
    for (int c = 0; c < 8; ++c)
        acc[c] *= alpha;
    int ph0 = __builtin_bit_cast(int, __builtin_amdgcn_cvt_pkrtz(p0[0], p0[1]));
    int ph1 = __builtin_bit_cast(int, __builtin_amdgcn_cvt_pkrtz(p0[2], p0[3]));
    int ph2 = __builtin_bit_cast(int, __builtin_amdgcn_cvt_pkrtz(p1[0], p1[1]));
    int ph3 = __builtin_bit_cast(int, __builtin_amdgcn_cvt_pkrtz(p1[2], p1[3]));
    const int s0 = (l15 + (((quad << 1)    ) & 3) * 16) * 4;
    const int s1 = (l15 + (((quad << 1) + 1) & 3) * 16) * 4;
    int a0 = __builtin_amdgcn_ds_bpermute(s0, ph0);
    int a1 = __builtin_amdgcn_ds_bpermute(s0, ph1);
    int a2 = __builtin_amdgcn_ds_bpermute(s1, ph0);
    int a3 = __builtin_amdgcn_ds_bpermute(s1, ph1);
    int b0 = __builtin_amdgcn_ds_bpermute(s0, ph2);
    int b1 = __builtin_amdgcn_ds_bpermute(s0, ph3);
    int b2 = __builtin_amdgcn_ds_bpermute(s1, ph2);
    int b3 = __builtin_amdgcn_ds_bpermute(s1, ph3);
    const bool lo = quad < 2;
    int4 pi = { lo ? a0 : b0, lo ? a1 : b1, lo ? a2 : b2, lo ? a3 : b3 };
    half8 pf = __builtin_bit_cast(half8, pi);
    for (int c = 0; c < 8; ++c)
        acc[c] = __builtin_amdgcn_mfma_f32_16x16x32_f16(va[c], pf, acc[c], 0, 0, 0);
}

__global__ __launch_bounds__(256) void attn_kernel(const _Float16* __restrict__ q,
                                                   const _Float16* __restrict__ k,
                                                   const _Float16* __restrict__ vt,
                                                   float* __restrict__ out) {
    __shared__ __align__(16) float Osh[4][16][132];
    __shared__ float msh[4][16];
    __shared__ float lsh[4][16];
    const int tid = threadIdx.x;
    const int lane = tid & 63, wv_ = tid >> 6;
    const int l15 = lane & 15, quad = lane >> 4;
    const int bidx = blockIdx.x;
    const int b = bidx & 1;
    const int t = 255 - (bidx >> 1);  // longest q-tiles first
    const int qb = t * 16;
    const int qg = qb + l15;

    const _Float16* qp = q + (size_t)(b * S_LEN + qb) * HD;
    half8 bq[4];
    for (int kk = 0; kk < 4; ++kk)
        bq[kk] = *(const half8*)&qp[l15 * HD + kk * 32 + quad * 8];

    f32x4 acc[8];
    for (int c = 0; c < 8; ++c) acc[c] = (f32x4){0.f, 0.f, 0.f, 0.f};
    float mrun = -1e30f, lrun = 0.f;

    const _Float16* kb = k + (size_t)b * S_LEN * HD;
    const _Float16* vtb = vt + (size_t)b * HD * S_LEN;

    const int nfull = (qb + 1) >> 5;  // unmasked 32-key tiles; then one masked tile
    const int kend = nfull * 32;
    const bool hasm = ((nfull & 3) == wv_);
    const int kb0 = wv_ * 32;

    half8 kf[8], kf2[8];
    if (kb0 < kend)      load_kf(kb, kb0, l15, quad, kf);
    else if (hasm)       load_kf(kb, kend, l15, quad, kf);
    for (int kbase = kb0; kbase < kend; kbase += 128) {
        const int kn = kbase + 128;
        if (kn < kend)   load_kf(kb, kn, l15, quad, kf2);   // next tile in flight
        else if (hasm)   load_kf(kb, kend, l15, quad, kf2);
        attn_tile<false>(kbase, qg, l15, quad, kf, vtb, bq, acc, mrun, lrun);
        for (int j = 0; j < 8; ++j) kf[j] = kf2[j];
    }
    if (hasm)
        attn_tile<true>(kend, qg, l15, quad, kf, vtb, bq, acc, mrun, lrun);

    for (int c = 0; c < 8; ++c)
        *(f32x4*)&Osh[wv_][l15][c * 16 + quad * 4] = acc[c];
    if (quad == 0) { msh[wv_][l15] = mrun; lsh[wv_][l15] = lrun; }
    __syncthreads();

    const int qr = tid >> 4, dg = (tid & 15) * 8;
    float m0 = msh[0][qr], m1 = msh[1][qr], m2 = msh[2][qr], m3 = msh[3][qr];
    float mm = fmaxf(fmaxf(m0, m1), fmaxf(m2, m3));
    float f0 = exp2f(m0 - mm), f1 = exp2f(m1 - mm), f2 = exp2f(m2 - mm), f3 = exp2f(m3 - mm);
    float l = lsh[0][qr] * f0 + lsh[1][qr] * f1 + lsh[2][qr] * f2 + lsh[3][qr] * f3;
    f32x4 oa = (f32x4){0.f, 0.f, 0.f, 0.f}, ob = oa;
    oa += *(f32x4*)&Osh[0][qr][dg] * f0;  ob += *(f32x4*)&Osh[0][qr][dg + 4] * f0;
    oa += *(f32x4*)&Osh[1][qr][dg] * f1;  ob += *(f32x4*)&Osh[1][qr][dg + 4] * f1;
    oa += *(f32x4*)&Osh[2][qr][dg] * f2;  ob += *(f32x4*)&Osh[2][qr][dg + 4] * f2;
    oa += *(f32x4*)&Osh[3][qr][dg] * f3;  ob += *(f32x4*)&Osh[3][qr][dg + 4] * f3;
    const float inv = 1.0f / l;
    float* op = out + (size_t)(b * S_LEN + qb + qr) * HD + dg;
    *(float4*)op       = (float4){oa[0] * inv, oa[1] * inv, oa[2] * inv, oa[3] * inv};
    *(float4*)(op + 4) = (float4){ob[0] * inv, ob[1] * inv, ob[2] * inv, ob[3] * inv};
}

extern "C" void kernel_launch(void* const* d_in, const int* in_sizes, int n_in,
                              void* d_out, int out_size, void* d_ws, size_t ws_size,
                              hipStream_t stream) {
    const float* x  = (const float*)d_in[0];
    const float* Wq = (const float*)d_in[1];
    const float* Wk = (const float*)d_in[2];
    const float* Wv = (const float*)d_in[3];
    float* out = (float*)d_out;
    char* ws = (char*)d_ws;
    _Float16* qw = (_Float16*)(ws);
    _Float16* kw = (_Float16*)(ws + (2u << 20));
    _Float16* vt = (_Float16*)(ws + (4u << 20));

    proj_kernel<<<dim3(3, 128), dim3(256), 0, stream>>>(x, Wq, Wk, Wv, qw, kw, vt);
    rope_kernel<<<dim3(2048), dim3(256), 0, stream>>>(qw, kw);
    attn_kernel<<<dim3(512), dim3(256), 0, stream>>>(qw, kw, vt, out);
}

// Round 8
// 364.624 us; speedup vs baseline: 2.0512x; 2.0512x over previous
//
#include <hip/hip_runtime.h>

typedef _Float16 half8 __attribute__((ext_vector_type(8)));
typedef _Float16 half2v __attribute__((ext_vector_type(2)));
typedef float f32x4 __attribute__((ext_vector_type(4)));

#define S_LEN 4096
#define D_DIM 4096
#define HD 128

// ws layout (6 MiB): qw [8192][128] f16 @0; kw @2MiB; vt [2][128][4096] f16 @4MiB

// ---------------- kernel 1: QKV projection GEMM (f16 MFMA) ----------------
// grid (3, 128): bx = projection, by = 64-row m-tile -> 384 blocks.
// 4 waves; wave-tile 64M x 32N. BK=32. Double-buffered LDS + 2-deep register
// prefetch, loop manually unrolled x2 so ALL register indexing is static
// (R7's pa[p] dynamic indexing spilled to scratch: 774 MB scratch writes).
#define ASTR 40   // staging row stride (f16)
#define QSTR 136  // epilogue row stride (f16)
__global__ __launch_bounds__(256) void proj_kernel(const float* __restrict__ x,
                                                   const float* __restrict__ wq,
                                                   const float* __restrict__ wk,
                                                   const float* __restrict__ wv,
                                                   _Float16* __restrict__ qw,
                                                   _Float16* __restrict__ kw,
                                                   _Float16* __restrict__ vt) {
    __shared__ __align__(16) _Float16 smem[17408];  // 2x7680 staging | epilogue union
    const int tid = threadIdx.x;
    const int bx = blockIdx.x;
    const int M0 = blockIdx.y * 64;
    const float* w = (bx == 0) ? wq : (bx == 1) ? wk : wv;
    const int lane = tid & 63, wv_ = tid >> 6;
    const int l15 = lane & 15, quad = lane >> 4;

    // staging: A 64x32 f32 (8 floats/thread), B 128x32 f32 (16 floats/thread)
    const int arow = tid >> 2, acol = (tid & 3) * 8;
    const int brow = tid >> 1, bcol = (tid & 1) * 16;
    const float* xa = x + (size_t)(M0 + arow) * D_DIM + acol;
    const float* wb = w + (size_t)brow * D_DIM + bcol;

    f32x4 acc[4][2];
    for (int mi = 0; mi < 4; ++mi)
        for (int ni = 0; ni < 2; ++ni)
            acc[mi][ni] = (f32x4){0.f, 0.f, 0.f, 0.f};

    auto stage = [&](_Float16* Ash, _Float16* Bsh, float4 A0, float4 A1,
                     float4 B0, float4 B1, float4 B2, float4 B3) {
        half8 ha = { (_Float16)A0.x, (_Float16)A0.y, (_Float16)A0.z, (_Float16)A0.w,
                     (_Float16)A1.x, (_Float16)A1.y, (_Float16)A1.z, (_Float16)A1.w };
        half8 hb0 = { (_Float16)B0.x, (_Float16)B0.y, (_Float16)B0.z, (_Float16)B0.w,
                      (_Float16)B1.x, (_Float16)B1.y, (_Float16)B1.z, (_Float16)B1.w };
        half8 hb1 = { (_Float16)B2.x, (_Float16)B2.y, (_Float16)B2.z, (_Float16)B2.w,
                      (_Float16)B3.x, (_Float16)B3.y, (_Float16)B3.z, (_Float16)B3.w };
        *(half8*)&Ash[arow * ASTR + acol] = ha;
        *(half8*)&Bsh[brow * ASTR + bcol] = hb0;
        *(half8*)&Bsh[brow * ASTR + bcol + 8] = hb1;
    };
    auto compute = [&](const _Float16* Ash, const _Float16* Bsh) {
        half8 af[4], bf[2];
        for (int mi = 0; mi < 4; ++mi)
            af[mi] = *(const half8*)&Ash[(mi * 16 + l15) * ASTR + quad * 8];
        for (int ni = 0; ni < 2; ++ni)
            bf[ni] = *(const half8*)&Bsh[(wv_ * 32 + ni * 16 + l15) * ASTR + quad * 8];
        for (int mi = 0; mi < 4; ++mi)
            for (int ni = 0; ni < 2; ++ni)
                acc[mi][ni] = __builtin_amdgcn_mfma_f32_16x16x32_f16(af[mi], bf[ni],
                                                                     acc[mi][ni], 0, 0, 0);
    };

#define LOADSET(Aa, Ab, Ba, Bb, Bc, Bd, off)                                  \
    Aa = *(const float4*)(xa + (off));     Ab = *(const float4*)(xa + (off) + 4);  \
    Ba = *(const float4*)(wb + (off));     Bb = *(const float4*)(wb + (off) + 4);  \
    Bc = *(const float4*)(wb + (off) + 8); Bd = *(const float4*)(wb + (off) + 12);

    float4 a0_0, a0_1, b0_0, b0_1, b0_2, b0_3;   // even-slab registers
    float4 a1_0, a1_1, b1_0, b1_1, b1_2, b1_3;   // odd-slab registers
    LOADSET(a0_0, a0_1, b0_0, b0_1, b0_2, b0_3, 0)
    LOADSET(a1_0, a1_1, b1_0, b1_1, b1_2, b1_3, 32)

    for (int i = 0; i < 128; i += 2) {
        // ---- half 0: slab i via LDS buf0 ----
        stage(smem, smem + 2560, a0_0, a0_1, b0_0, b0_1, b0_2, b0_3);
        if (i + 2 < 128) {
            const int off = (i + 2) * 32;
            LOADSET(a0_0, a0_1, b0_0, b0_1, b0_2, b0_3, off)
        }
        __syncthreads();
        compute(smem, smem + 2560);
        // ---- half 1: slab i+1 via LDS buf1 ----
        stage(smem + 7680, smem + 10240, a1_0, a1_1, b1_0, b1_1, b1_2, b1_3);
        if (i + 3 < 128) {
            const int off = (i + 3) * 32;
            LOADSET(a1_0, a1_1, b1_0, b1_1, b1_2, b1_3, off)
        }
        __syncthreads();
        compute(smem + 7680, smem + 10240);
        // no trailing barrier: next half's barrier orders buf reuse
    }
#undef LOADSET
    __syncthreads();

    // ---- epilogue via LDS (coalesced 16B stores). C row(M) = mi*16+quad*4+r,
    // col(N/hd) = wv_*32 + ni*16 + l15 ---- (verified R6/R7)
    if (bx < 2) {
        for (int mi = 0; mi < 4; ++mi)
            for (int ni = 0; ni < 2; ++ni)
                for (int r = 0; r < 4; ++r)
                    smem[(mi * 16 + quad * 4 + r) * QSTR + wv_ * 32 + ni * 16 + l15] =
                        (_Float16)acc[mi][ni][r];
        __syncthreads();
        _Float16* dst = ((bx == 0) ? qw : kw) + (size_t)M0 * HD;
        const int row = tid >> 2, c0 = (tid & 3) * 32;
        for (int j = 0; j < 4; ++j)
            *(half8*)&dst[row * HD + c0 + j * 8] = *(const half8*)&smem[row * QSTR + c0 + j * 8];
    } else {
        // transpose in LDS: smem[hd][s_local]
        for (int mi = 0; mi < 4; ++mi)
            for (int ni = 0; ni < 2; ++ni)
                for (int r = 0; r < 4; ++r)
                    smem[(wv_ * 32 + ni * 16 + l15) * QSTR + mi * 16 + quad * 4 + r] =
                        (_Float16)acc[mi][ni][r];
        __syncthreads();
        _Float16* dst = vt + (size_t)(M0 >> 12) * HD * S_LEN + (M0 & (S_LEN - 1));
        const int hd = tid >> 1, s0 = (tid & 1) * 32;
        for (int j = 0; j < 4; ++j)
            *(half8*)&dst[(size_t)hd * S_LEN + s0 + j * 8] =
                *(const half8*)&smem[hd * QSTR + s0 + j * 8];
    }
}

// ---------------- kernel 2: RoPE on q,k in place (verified, unchanged) ----------------
__global__ __launch_bounds__(256) void rope_kernel(_Float16* __restrict__ qw,
                                                   _Float16* __restrict__ kw) {
    const int g = blockIdx.x * 256 + threadIdx.x;  // 524288
    const int m = g >> 6, p = g & 63;
    const int s = m & (S_LEN - 1);
    const float theta = exp2f((float)p * -0.4152410118609203f);  // 10000^(-p/32)
    float sn, cn;
    sincosf((float)s * theta, &sn, &cn);
    const size_t off = (size_t)m * HD + 2 * p;
    half2v qv = *(half2v*)&qw[off];
    half2v kv = *(half2v*)&kw[off];
    float q0 = qv[0], q1 = qv[1], k0 = kv[0], k1 = kv[1];
    half2v qo = { (_Float16)(q0 * cn - q1 * sn), (_Float16)(q1 * cn + q0 * sn) };
    half2v ko = { (_Float16)(k0 * cn - k1 * sn), (_Float16)(k1 * cn + k0 * sn) };
    *(half2v*)&qw[off] = qo;
    *(half2v*)&kw[off] = ko;
}

// ---------------- kernel 3: attention — R3-verified core + K-frag prefetch ----------------
__device__ __forceinline__ void load_kf(const _Float16* __restrict__ kb, int kbase,
                                        int l15, int quad, half8* kf) {
    const _Float16* kr = kb + (size_t)(kbase + l15) * HD + quad * 8;
    for (int kk = 0; kk < 4; ++kk) {
        kf[kk]     = *(const half8*)(kr + kk * 32);
        kf[4 + kk] = *(const half8*)(kr + 16 * HD + kk * 32);
    }
}

template<bool MASKED>
__device__ __forceinline__ void attn_tile(int kbase, int qg, int l15, int quad,
                                          const half8* kf,
                                          const _Float16* __restrict__ vtb,
                                          const half8* bq, f32x4* acc,
                                          float& mrun, float& lrun) {
    const float csc = 0.1275174348796053f;  // (1/sqrt(128)) * log2(e)
    f32x4 st0 = (f32x4){0.f, 0.f, 0.f, 0.f};
    f32x4 st1 = (f32x4){0.f, 0.f, 0.f, 0.f};
    for (int kk = 0; kk < 4; ++kk) {
        st0 = __builtin_amdgcn_mfma_f32_16x16x32_f16(kf[kk],     bq[kk], st0, 0, 0, 0);
        st1 = __builtin_amdgcn_mfma_f32_16x16x32_f16(kf[4 + kk], bq[kk], st1, 0, 0, 0);
    }
    half8 va[8];
    const _Float16* vr = vtb + (size_t)l15 * S_LEN + kbase + quad * 8;
    for (int c = 0; c < 8; ++c)
        va[c] = *(const half8*)(vr + (size_t)c * 16 * S_LEN);
    float p0[4], p1[4];
    float mloc = -1e30f;
    for (int r = 0; r < 4; ++r) {
        float v0 = st0[r] * csc;
        float v1 = st1[r] * csc;
        if (MASKED) {
            const int key0 = kbase + quad * 4 + r;
            if (key0 > qg)      v0 = -1e30f;
            if (key0 + 16 > qg) v1 = -1e30f;
        }
        p0[r] = v0; p1[r] = v1;
        mloc = fmaxf(mloc, fmaxf(v0, v1));
    }
    mloc = fmaxf(mloc, __shfl_xor(mloc, 16));
    mloc = fmaxf(mloc, __shfl_xor(mloc, 32));
    const float mnew = fmaxf(mrun, mloc);
    const float alpha = exp2f(mrun - mnew);
    mrun = mnew;
    float ls = 0.f;
    for (int r = 0; r < 4; ++r) {
        p0[r] = exp2f(p0[r] - mnew);
        p1[r] = exp2f(p1[r] - mnew);
        ls += p0[r] + p1[r];
    }
    ls += __shfl_xor(ls, 16);
    ls += __shfl_xor(ls, 32);
    lrun = lrun * alpha + ls;
    for (int c = 0; c < 8; ++c)
        acc[c] *= alpha;
    int ph0 = __builtin_bit_cast(int, __builtin_amdgcn_cvt_pkrtz(p0[0], p0[1]));
    int ph1 = __builtin_bit_cast(int, __builtin_amdgcn_cvt_pkrtz(p0[2], p0[3]));
    int ph2 = __builtin_bit_cast(int, __builtin_amdgcn_cvt_pkrtz(p1[0], p1[1]));
    int ph3 = __builtin_bit_cast(int, __builtin_amdgcn_cvt_pkrtz(p1[2], p1[3]));
    const int s0 = (l15 + (((quad << 1)    ) & 3) * 16) * 4;
    const int s1 = (l15 + (((quad << 1) + 1) & 3) * 16) * 4;
    int a0 = __builtin_amdgcn_ds_bpermute(s0, ph0);
    int a1 = __builtin_amdgcn_ds_bpermute(s0, ph1);
    int a2 = __builtin_amdgcn_ds_bpermute(s1, ph0);
    int a3 = __builtin_amdgcn_ds_bpermute(s1, ph1);
    int b0 = __builtin_amdgcn_ds_bpermute(s0, ph2);
    int b1 = __builtin_amdgcn_ds_bpermute(s0, ph3);
    int b2 = __builtin_amdgcn_ds_bpermute(s1, ph2);
    int b3 = __builtin_amdgcn_ds_bpermute(s1, ph3);
    const bool lo = quad < 2;
    int4 pi = { lo ? a0 : b0, lo ? a1 : b1, lo ? a2 : b2, lo ? a3 : b3 };
    half8 pf = __builtin_bit_cast(half8, pi);
    for (int c = 0; c < 8; ++c)
        acc[c] = __builtin_amdgcn_mfma_f32_16x16x32_f16(va[c], pf, acc[c], 0, 0, 0);
}

__global__ __launch_bounds__(256) void attn_kernel(const _Float16* __restrict__ q,
                                                   const _Float16* __restrict__ k,
                                                   const _Float16* __restrict__ vt,
                                                   float* __restrict__ out) {
    __shared__ __align__(16) float Osh[4][16][132];
    __shared__ float msh[4][16];
    __shared__ float lsh[4][16];
    const int tid = threadIdx.x;
    const int lane = tid & 63, wv_ = tid >> 6;
    const int l15 = lane & 15, quad = lane >> 4;
    const int bidx = blockIdx.x;
    const int b = bidx & 1;
    const int t = 255 - (bidx >> 1);  // longest q-tiles first
    const int qb = t * 16;
    const int qg = qb + l15;

    const _Float16* qp = q + (size_t)(b * S_LEN + qb) * HD;
    half8 bq[4];
    for (int kk = 0; kk < 4; ++kk)
        bq[kk] = *(const half8*)&qp[l15 * HD + kk * 32 + quad * 8];

    f32x4 acc[8];
    for (int c = 0; c < 8; ++c) acc[c] = (f32x4){0.f, 0.f, 0.f, 0.f};
    float mrun = -1e30f, lrun = 0.f;

    const _Float16* kb = k + (size_t)b * S_LEN * HD;
    const _Float16* vtb = vt + (size_t)b * HD * S_LEN;

    const int nfull = (qb + 1) >> 5;  // unmasked 32-key tiles; then one masked tile
    const int kend = nfull * 32;
    const bool hasm = ((nfull & 3) == wv_);
    const int kb0 = wv_ * 32;

    half8 kf[8], kf2[8];
    if (kb0 < kend)      load_kf(kb, kb0, l15, quad, kf);
    else if (hasm)       load_kf(kb, kend, l15, quad, kf);
    for (int kbase = kb0; kbase < kend; kbase += 128) {
        const int kn = kbase + 128;
        if (kn < kend)   load_kf(kb, kn, l15, quad, kf2);   // next tile in flight
        else if (hasm)   load_kf(kb, kend, l15, quad, kf2);
        attn_tile<false>(kbase, qg, l15, quad, kf, vtb, bq, acc, mrun, lrun);
        for (int j = 0; j < 8; ++j) kf[j] = kf2[j];
    }
    if (hasm)
        attn_tile<true>(kend, qg, l15, quad, kf, vtb, bq, acc, mrun, lrun);

    for (int c = 0; c < 8; ++c)
        *(f32x4*)&Osh[wv_][l15][c * 16 + quad * 4] = acc[c];
    if (quad == 0) { msh[wv_][l15] = mrun; lsh[wv_][l15] = lrun; }
    __syncthreads();

    const int qr = tid >> 4, dg = (tid & 15) * 8;
    float m0 = msh[0][qr], m1 = msh[1][qr], m2 = msh[2][qr], m3 = msh[3][qr];
    float mm = fmaxf(fmaxf(m0, m1), fmaxf(m2, m3));
    float f0 = exp2f(m0 - mm), f1 = exp2f(m1 - mm), f2 = exp2f(m2 - mm), f3 = exp2f(m3 - mm);
    float l = lsh[0][qr] * f0 + lsh[1][qr] * f1 + lsh[2][qr] * f2 + lsh[3][qr] * f3;
    f32x4 oa = (f32x4){0.f, 0.f, 0.f, 0.f}, ob = oa;
    oa += *(f32x4*)&Osh[0][qr][dg] * f0;  ob += *(f32x4*)&Osh[0][qr][dg + 4] * f0;
    oa += *(f32x4*)&Osh[1][qr][dg] * f1;  ob += *(f32x4*)&Osh[1][qr][dg + 4] * f1;
    oa += *(f32x4*)&Osh[2][qr][dg] * f2;  ob += *(f32x4*)&Osh[2][qr][dg + 4] * f2;
    oa += *(f32x4*)&Osh[3][qr][dg] * f3;  ob += *(f32x4*)&Osh[3][qr][dg + 4] * f3;
    const float inv = 1.0f / l;
    float* op = out + (size_t)(b * S_LEN + qb + qr) * HD + dg;
    *(float4*)op       = (float4){oa[0] * inv, oa[1] * inv, oa[2] * inv, oa[3] * inv};
    *(float4*)(op + 4) = (float4){ob[0] * inv, ob[1] * inv, ob[2] * inv, ob[3] * inv};
}

extern "C" void kernel_launch(void* const* d_in, const int* in_sizes, int n_in,
                              void* d_out, int out_size, void* d_ws, size_t ws_size,
                              hipStream_t stream) {
    const float* x  = (const float*)d_in[0];
    const float* Wq = (const float*)d_in[1];
    const float* Wk = (const float*)d_in[2];
    const float* Wv = (const float*)d_in[3];
    float* out = (float*)d_out;
    char* ws = (char*)d_ws;
    _Float16* qw = (_Float16*)(ws);
    _Float16* kw = (_Float16*)(ws + (2u << 20));
    _Float16* vt = (_Float16*)(ws + (4u << 20));

    proj_kernel<<<dim3(3, 128), dim3(256), 0, stream>>>(x, Wq, Wk, Wv, qw, kw, vt);
    rope_kernel<<<dim3(2048), dim3(256), 0, stream>>>(qw, kw);
    attn_kernel<<<dim3(512), dim3(256), 0, stream>>>(qw, kw, vt, out);
}